// Round 8
// baseline (86.575 us; speedup 1.0000x reference)
//
#include <hip/hip_runtime.h>

#define BB 8
#define XX 256
#define CC 256
#define TC 4          // c-rows per k_go / k_all block
#define TCE 4         // c-rows per epilogue call (epilogue unchanged from R7)
#define NCH 4         // x-chunks; matches R7's SPLIT=4 fold tree bitwise
#define XCH (XX / NCH)   // 64 x-rows per chunk

// R15: move the c-column broadcast off the LDS pipe.
// Cross-round fit (R9 gives gaps ~16 us, fill 41.5): R14's k_go ~25 us,
// and R12->R14 showed dropping the 64 KB LDS tile saved only ~4 us -> the
// shared cost is the per-x ds_read_b128 broadcast: per CU 8 waves x 256
// iters x ~12 cyc ~ 10 us serialized on the single LDS pipe, on top of
// ~10 instr/iter for 5 useful FMAs at 2 blocks/CU (grid-capped).
// Fix: cols are wave-uniform (address has no threadIdx) -> read them as
// uniform global loads; hipcc scalarizes to s_load_dwordx4 via the constant
// cache (scalar pipe, no LDS, no VALU slots; v_fmac takes the SGPR operand).
// Staging + its barrier deleted; LDS keeps only sS + wmax.
// Bitwise: identical values, identical FMA order -> absmax 0.0 expected.
// Worst case (no scalarization): same-address flat loads served by one L1
// line ~ status quo.

// ---------------- shared epilogue (bitwise R5..R14) ----------------

__device__ __forceinline__ void epilogue(
    float dist0, float dist1, float dist2, float dist3,
    int b, int c0, int d, const float* __restrict__ gu,
    float* __restrict__ out, float (*wmax)[4])
{
    float ed[TCE];
    ed[0] = (d == c0)     ? 0.0f : __fdiv_rn(1.0f, __fadd_rn(dist0, 1e-10f));
    ed[1] = (d == c0 + 1) ? 0.0f : __fdiv_rn(1.0f, __fadd_rn(dist1, 1e-10f));
    ed[2] = (d == c0 + 2) ? 0.0f : __fdiv_rn(1.0f, __fadd_rn(dist2, 1e-10f));
    ed[3] = (d == c0 + 3) ? 0.0f : __fdiv_rn(1.0f, __fadd_rn(dist3, 1e-10f));

    const int wave = threadIdx.x >> 6;
    const int lane = threadIdx.x & 63;
#pragma unroll
    for (int j = 0; j < TCE; ++j) {
        float v = ed[j];
#pragma unroll
        for (int m = 1; m < 64; m <<= 1) v = fmaxf(v, __shfl_xor(v, m));
        if (lane == 0) wmax[j][wave] = v;
    }
    __syncthreads();

#pragma unroll
    for (int j = 0; j < TCE; ++j) {
        const int c = c0 + j;
        float em = fmaxf(fmaxf(wmax[j][0], wmax[j][1]), fmaxf(wmax[j][2], wmax[j][3]));
        float p;
        if (d == c) {
            p = 0.99f;
        } else {
            p = __fmul_rn(__fdiv_rn(ed[j], em), 0.99f);
        }
        float logit = logf(__fdiv_rn(p, __fsub_rn(1.0f, p)));

        const float2 g2 = *(const float2*)(gu + (((size_t)b * CC + c) * CC + d) * 2);
        float g0 = -logf(-logf(g2.x));
        float g1 = -logf(-logf(g2.y));

        float a0 = __fadd_rn(logit, g0);
        float a1 = __fadd_rn(-logit, g1);
        float m  = fmaxf(a0, a1);
        float e0 = expf(__fsub_rn(a0, m));
        float e1 = expf(__fsub_rn(a1, m));
        float s  = __fadd_rn(e0, e1);
        float y0 = __fdiv_rn(e0, s);
        float y1 = __fdiv_rn(e1, s);
        if (y0 > y1) {
            atomicAdd(&out[(size_t)c * CC + d], 0.125f);
        }
    }
}

// ---------------- Path A: k_u + k_go (ws available) ----------------

// k_u: u = wa*amp + wp*ph for all B*X*C; blocks 0..63 also zero `out`.
// (R7's k_u, verbatim -> identical u bits.)
__global__ __launch_bounds__(256) void k_u(
    const float* __restrict__ amp, const float* __restrict__ ph,
    const float* __restrict__ wAp, const float* __restrict__ wPp,
    float* __restrict__ u, float* __restrict__ out)
{
    const float wa = wAp[0], wp = wPp[0];
    const int i = blockIdx.x * 256 + threadIdx.x;   // float4 index, exact cover
    const float4 a = ((const float4*)amp)[i];
    const float4 p = ((const float4*)ph)[i];
    float4 r;
    r.x = __fadd_rn(__fmul_rn(wa, a.x), __fmul_rn(wp, p.x));
    r.y = __fadd_rn(__fmul_rn(wa, a.y), __fmul_rn(wp, p.y));
    r.z = __fadd_rn(__fmul_rn(wa, a.z), __fmul_rn(wp, p.z));
    r.w = __fadd_rn(__fmul_rn(wa, a.w), __fmul_rn(wp, p.w));
    ((float4*)u)[i] = r;

    if (blockIdx.x < 64) {            // 64 blocks * 256 thr * 16B = 256 KB = out
        ((float4*)out)[blockIdx.x * 256 + threadIdx.x] = make_float4(0.f, 0.f, 0.f, 0.f);
    }
}

// k_go: gram from global u (scalar-cached uniform cols) + epilogue, fused.
__global__ __launch_bounds__(256) void k_go(
    const float* __restrict__ u,  const float* __restrict__ A,
    const float* __restrict__ gu, float* __restrict__ out)
{
    const int d  = threadIdx.x;
    const int c0 = blockIdx.x * TC;
    const int b  = blockIdx.y;

    __shared__ float sS[CC];          // per-chunk S_d exchange
    __shared__ float wmax[TCE][4];

    const float* ucol  = u + (size_t)b * XX * CC + d;    // per-lane stream
    const float* ucols = u + (size_t)b * XX * CC + c0;   // wave-uniform (no tid)

    float w0 = 0.f, w1 = 0.f, w2 = 0.f, w3 = 0.f;

#pragma unroll
    for (int h = 0; h < NCH; ++h) {
        const int x0 = h * XCH;
        float gacc0 = 0.f, gacc1 = 0.f, gacc2 = 0.f, gacc3 = 0.f, sacc = 0.f;
#pragma unroll 8
        for (int x = 0; x < XCH; ++x) {
            const size_t ro = (size_t)(x0 + x) * CC;
            const float ud  = ucol[ro];          // coalesced per-lane global
            const float cv0 = ucols[ro + 0];     // uniform -> s_load (K$)
            const float cv1 = ucols[ro + 1];
            const float cv2 = ucols[ro + 2];
            const float cv3 = ucols[ro + 3];
            gacc0 = fmaf(cv0, ud, gacc0);
            gacc1 = fmaf(cv1, ud, gacc1);
            gacc2 = fmaf(cv2, ud, gacc2);
            gacc3 = fmaf(cv3, ud, gacc3);
            sacc  = fmaf(ud, ud, sacc);
        }
        __syncthreads();          // previous fold's sS reads are done
        sS[d] = sacc;
        __syncthreads();

        // per-chunk partial, identical chain to R7/R12/R14
        const float t0 = fmaf(-2.0f, gacc0, __fadd_rn(sS[c0 + 0], sacc));
        const float t1 = fmaf(-2.0f, gacc1, __fadd_rn(sS[c0 + 1], sacc));
        const float t2 = fmaf(-2.0f, gacc2, __fadd_rn(sS[c0 + 2], sacc));
        const float t3 = fmaf(-2.0f, gacc3, __fadd_rn(sS[c0 + 3], sacc));
        if (h == 0) {
            w0 = t0; w1 = t1; w2 = t2; w3 = t3;
        } else {
            // same left-associated fold: ((w0+w1)+w2)+w3
            w0 = __fadd_rn(w0, t0); w1 = __fadd_rn(w1, t1);
            w2 = __fadd_rn(w2, t2); w3 = __fadd_rn(w3, t3);
        }
    }

    const float dAd  = A[(size_t)d * CC + d];
    const float dAd2 = __fmul_rn(dAd, dAd);

    epilogue(__fmul_rn(dAd2, w0), __fmul_rn(dAd2, w1),
             __fmul_rn(dAd2, w2), __fmul_rn(dAd2, w3),
             b, c0, d, gu, out, wmax);
}

// ---------------- Path B fallback: R12's k_zero + k_all (no ws) ----------------

__global__ __launch_bounds__(256) void k_zero(float* __restrict__ out)
{
    ((float4*)out)[blockIdx.x * 256 + threadIdx.x] = make_float4(0.f, 0.f, 0.f, 0.f);
}

__global__ __launch_bounds__(256) void k_all(
    const float* __restrict__ amp, const float* __restrict__ ph,
    const float* __restrict__ A,   const float* __restrict__ wAp,
    const float* __restrict__ wPp, const float* __restrict__ gu,
    float* __restrict__ out)
{
    const int d  = threadIdx.x;
    const int c0 = blockIdx.x * TC;
    const int b  = blockIdx.y;

    const float wa = wAp[0];
    const float wp = wPp[0];

    __shared__ float uT[XCH * CC];    // u[b, x0:x0+64, 0:256], 64 KB
    __shared__ float sS[CC];
    __shared__ float wmax[TCE][4];

    float w0 = 0.f, w1 = 0.f, w2 = 0.f, w3 = 0.f;

    for (int h = 0; h < NCH; ++h) {
        {
            const float4* aS = (const float4*)(amp + ((size_t)b * XX + h * XCH) * CC);
            const float4* pS = (const float4*)(ph  + ((size_t)b * XX + h * XCH) * CC);
            float4* uT4 = (float4*)uT;
#pragma unroll 8
            for (int k = 0; k < (XCH * CC / 4) / 256; ++k) {   // 16 iters
                const int idx = k * 256 + threadIdx.x;
                const float4 a = aS[idx];
                const float4 p = pS[idx];
                float4 uu;
                uu.x = __fadd_rn(__fmul_rn(wa, a.x), __fmul_rn(wp, p.x));
                uu.y = __fadd_rn(__fmul_rn(wa, a.y), __fmul_rn(wp, p.y));
                uu.z = __fadd_rn(__fmul_rn(wa, a.z), __fmul_rn(wp, p.z));
                uu.w = __fadd_rn(__fmul_rn(wa, a.w), __fmul_rn(wp, p.w));
                uT4[idx] = uu;
            }
        }
        __syncthreads();

        float gacc0 = 0.f, gacc1 = 0.f, gacc2 = 0.f, gacc3 = 0.f, sacc = 0.f;
#pragma unroll 4
        for (int x = 0; x < XCH; ++x) {
            const float* row = uT + x * CC;
            const float ud  = row[d];
            const float4 cA = *(const float4*)(row + c0);
            gacc0 = fmaf(cA.x, ud, gacc0);
            gacc1 = fmaf(cA.y, ud, gacc1);
            gacc2 = fmaf(cA.z, ud, gacc2);
            gacc3 = fmaf(cA.w, ud, gacc3);
            sacc  = fmaf(ud, ud, sacc);
        }
        __syncthreads();
        sS[d] = sacc;
        __syncthreads();

        const float t0 = fmaf(-2.0f, gacc0, __fadd_rn(sS[c0 + 0], sacc));
        const float t1 = fmaf(-2.0f, gacc1, __fadd_rn(sS[c0 + 1], sacc));
        const float t2 = fmaf(-2.0f, gacc2, __fadd_rn(sS[c0 + 2], sacc));
        const float t3 = fmaf(-2.0f, gacc3, __fadd_rn(sS[c0 + 3], sacc));
        if (h == 0) {
            w0 = t0; w1 = t1; w2 = t2; w3 = t3;
        } else {
            w0 = __fadd_rn(w0, t0); w1 = __fadd_rn(w1, t1);
            w2 = __fadd_rn(w2, t2); w3 = __fadd_rn(w3, t3);
        }
    }

    const float dAd  = A[(size_t)d * CC + d];
    const float dAd2 = __fmul_rn(dAd, dAd);

    epilogue(__fmul_rn(dAd2, w0), __fmul_rn(dAd2, w1),
             __fmul_rn(dAd2, w2), __fmul_rn(dAd2, w3),
             b, c0, d, gu, out, wmax);
}

extern "C" void kernel_launch(void* const* d_in, const int* in_sizes, int n_in,
                              void* d_out, int out_size, void* d_ws, size_t ws_size,
                              hipStream_t stream) {
    const float* amp = (const float*)d_in[0];
    const float* ph  = (const float*)d_in[1];
    const float* A   = (const float*)d_in[2];
    const float* wa  = (const float*)d_in[3];
    const float* wp  = (const float*)d_in[4];
    const float* gu  = (const float*)d_in[5];
    float* out = (float*)d_out;

    const size_t uElems = (size_t)BB * XX * CC;                // 2 MB
    if (ws_size >= uElems * sizeof(float)) {
        float* ud = (float*)d_ws;          // fully written by k_u before k_go
        k_u<<<(int)(uElems / 4 / 256), 256, 0, stream>>>(amp, ph, wa, wp, ud, out);
        dim3 g(CC / TC, BB);
        k_go<<<g, 256, 0, stream>>>(ud, A, gu, out);
    } else {
        k_zero<<<(CC * CC / 4) / 256, 256, 0, stream>>>(out);
        dim3 g(CC / TC, BB);
        k_all<<<g, 256, 0, stream>>>(amp, ph, A, wa, wp, gu, out);
    }
}